// Round 8
// baseline (3837.917 us; speedup 1.0000x reference)
//
#include <hip/hip_runtime.h>

#define BB 8
#define NN 8192
#define MM 512
#define KK 6
#define NSAMP 16
#define CC 13
#define DD 64

typedef float v2f __attribute__((ext_vector_type(2)));

// ---- output slot offsets (in floats) ----
#define O_ASSO   0u          // final_asso      (B,N,K)  393216
#define O_CIDX   393216u     // cluster_idx     (B,M)    4096
#define O_C2P    397312u     // c2p_idx         (B,N,K)  393216
#define O_C2PA   790528u     // c2p_idx_abs     (B,N,K)  393216
#define O_OUT    1183744u    // out             (B,N,C)  851968
#define O_RPXYZ  2035712u    // re_p_xyz        (B,N,3)  196608
#define O_RPLAB  2232320u    // re_p_label      (B,N,C)  851968
#define O_FDIST  3084288u    // fea_dist        (B,N,K)  393216
#define O_PFEA   3477504u    // p_fea           (B,N,D)  4194304
#define O_SPLABT 7671808u    // sp_label^T      (B,C,M)  53248
#define O_PSLAB  7725056u    // sp_pseudo_lab   (B,M)    4096
#define O_PSOH   7729152u    // sp_pseudo_oh    (B,C,M)  53248

// ---- DPP wave64 max-reduce of a u64 key; valid result in lane 63 ----
__device__ __forceinline__ unsigned long long dpp_max_u64(unsigned long long k) {
  int lo = (int)(unsigned)(k & 0xFFFFFFFFull);
  int hi = (int)(unsigned)(k >> 32);
#define DPP_STEP(ctrl)                                                         \
  {                                                                            \
    int nlo = __builtin_amdgcn_update_dpp(0, lo, ctrl, 0xf, 0xf, true);        \
    int nhi = __builtin_amdgcn_update_dpp(0, hi, ctrl, 0xf, 0xf, true);        \
    unsigned long long nk =                                                    \
        ((unsigned long long)(unsigned)nhi << 32) | (unsigned)nlo;             \
    unsigned long long ck =                                                    \
        ((unsigned long long)(unsigned)hi << 32) | (unsigned)lo;               \
    if (nk > ck) { lo = nlo; hi = nhi; }                                       \
  }
  DPP_STEP(0x111)  // row_shr:1
  DPP_STEP(0x112)  // row_shr:2
  DPP_STEP(0x114)  // row_shr:4
  DPP_STEP(0x118)  // row_shr:8  -> lane15/31/47/63 hold row maxima
  DPP_STEP(0x142)  // row_bcast:15 -> lane31=max(r0,r1), lane63=max(r2,r3)
  DPP_STEP(0x143)  // row_bcast:31 -> lane63=max(all)
#undef DPP_STEP
  return ((unsigned long long)(unsigned)hi << 32) | (unsigned)lo;
}

// ================= FPS: one 512-thread block per batch, 16 pts/thread ============
// Points held as 8 float2 pairs (streams A: p=t+2j*512, B: p=t+(2j+1)*512) so the
// distance core lowers to v_pk_{add,mul}_f32. fp contract(off) keeps numpy-exact
// rounding (separate mul+add, no FMA). Per-stream argmax + u64-key merge keeps
// the first-max (smallest index) tie rule bit-exact.
__global__ __launch_bounds__(512, 1) void k_fps(const float* __restrict__ pc,
                                                int* __restrict__ cidx,
                                                float* __restrict__ cxyz,
                                                float* __restrict__ out) {
#pragma clang fp contract(off)
  __shared__ float sx[NN], sy[NN], sz[NN];
  __shared__ unsigned long long s_best[2][8];
  __shared__ int   s_pidx[MM];
  __shared__ float s_px[MM], s_py[MM], s_pz[MM];
  const int t = threadIdx.x;
  const int b = blockIdx.x;
  const float* xb = pc + (size_t)b * NN * 6;
  v2f px[8], py[8], pz[8], dist[8];
#pragma unroll
  for (int j = 0; j < 8; ++j) {
    int p0 = t + (2*j)*512, p1 = t + (2*j+1)*512;
    float X0 = xb[(size_t)p0*6+0], Y0 = xb[(size_t)p0*6+1], Z0 = xb[(size_t)p0*6+2];
    float X1 = xb[(size_t)p1*6+0], Y1 = xb[(size_t)p1*6+1], Z1 = xb[(size_t)p1*6+2];
    px[j] = (v2f){X0, X1}; py[j] = (v2f){Y0, Y1}; pz[j] = (v2f){Z0, Z1};
    dist[j] = (v2f){1e10f, 1e10f};
    sx[p0] = X0; sy[p0] = Y0; sz[p0] = Z0;
    sx[p1] = X1; sy[p1] = Y1; sz[p1] = Z1;
  }
  __syncthreads();
  float lx = sx[0], ly = sy[0], lz = sz[0];
  if (t == 0) { s_pidx[0] = 0; s_px[0] = lx; s_py[0] = ly; s_pz[0] = lz; }
  const int lane = t & 63, wave = t >> 6;
  for (int step = 1; step < MM; ++step) {
    float bvA = -1.0f, bvB = -1.0f; int bpA = 0, bpB = 0;
#pragma unroll
    for (int j = 0; j < 8; ++j) {
      v2f dx = px[j] - lx, dy = py[j] - ly, dz = pz[j] - lz;
      v2f d = (dx*dx + dy*dy) + dz*dz;       // contract(off): exact numpy order
      v2f nd = __builtin_elementwise_min(dist[j], d);
      dist[j] = nd;
      float nA = nd.x, nB = nd.y;
      if (nA > bvA) { bvA = nA; bpA = t + (2*j)*512; }    // stream A: p ascending
      if (nB > bvB) { bvB = nB; bpB = t + (2*j+1)*512; }  // stream B: p ascending
    }
    // exact tie handling across streams via packed keys (tie -> smaller p)
    unsigned long long kA = ((unsigned long long)__float_as_uint(bvA) << 32)
                          | (unsigned)(0xFFFFFFFFu - (unsigned)bpA);
    unsigned long long kB = ((unsigned long long)__float_as_uint(bvB) << 32)
                          | (unsigned)(0xFFFFFFFFu - (unsigned)bpB);
    unsigned long long key = (kB > kA) ? kB : kA;
    key = dpp_max_u64(key);              // VALU-only wave reduce; lane 63 valid
    if (lane == 63) s_best[step & 1][wave] = key;
    __syncthreads();                     // single barrier (parity dbuf)
    const ulonglong2* sb = (const ulonglong2*)s_best[step & 1];
    ulonglong2 q0 = sb[0], q1 = sb[1], q2 = sb[2], q3 = sb[3];
    unsigned long long kk = q0.x;
    if (q0.y > kk) kk = q0.y;
    if (q1.x > kk) kk = q1.x;
    if (q1.y > kk) kk = q1.y;
    if (q2.x > kk) kk = q2.x;
    if (q2.y > kk) kk = q2.y;
    if (q3.x > kk) kk = q3.x;
    if (q3.y > kk) kk = q3.y;
    int p = (int)(0xFFFFFFFFu - (unsigned)(kk & 0xFFFFFFFFull));
    lx = sx[p]; ly = sy[p]; lz = sz[p];  // LDS broadcast
    if (t == 0) {                        // LDS staging only
      s_pidx[step] = p;
      s_px[step] = lx; s_py[step] = ly; s_pz[step] = lz;
    }
  }
  __syncthreads();
  // coalesced epilogue: write all selected indices/coords once
  if (t < MM) {
    int p = s_pidx[t];
    cidx[b*MM + t] = p;
    out[O_CIDX + b*MM + t] = (float)p;
    cxyz[((size_t)b*MM + t)*3+0] = s_px[t];
    cxyz[((size_t)b*MM + t)*3+1] = s_py[t];
    cxyz[((size_t)b*MM + t)*3+2] = s_pz[t];
  }
}

// ================= pack + p_fea + head: 1 point/thread, no LDS ===================
// (3,8): reg cap 170 (live ~120, no spill) + >=3 waves/SIMD to hide s_load stalls.
__attribute__((amdgpu_waves_per_eu(3, 8)))
__global__ __launch_bounds__(256) void k_pfea(const float* __restrict__ pc,
                                              const float* __restrict__ knn,
                                              const float* __restrict__ Wk1,
                                              const float* __restrict__ Wk2,
                                              const float* __restrict__ Wg,
                                              const float* __restrict__ hW1,
                                              const float* __restrict__ hW2,
                                              float* __restrict__ xyz,
                                              float* __restrict__ out) {
  int i = blockIdx.x * 256 + threadIdx.x;
  const float2* pr = (const float2*)(pc + (size_t)i*6);
  float2 r0 = pr[0], r1 = pr[1], r2 = pr[2];
  float* xo = xyz + (size_t)i*3;
  xo[0] = r0.x; xo[1] = r0.y; xo[2] = r1.x;
  float acc[DD];
#pragma unroll
  for (int d = 0; d < DD; ++d) acc[d] = -3.4e38f;
  const float* kp = knn + (size_t)i * NSAMP * 2;
  for (int s = 0; s < NSAMP; ++s) {
    float u = kp[s*2+0], v2 = kp[s*2+1];
    float h1[32];
#pragma unroll
    for (int j = 0; j < 32; ++j) h1[j] = fmaxf(u*Wk1[j] + v2*Wk1[32+j], 0.f);
#pragma unroll
    for (int d = 0; d < DD; ++d) {
      float tt = 0.f;
#pragma unroll
      for (int j = 0; j < 32; ++j) tt += h1[j]*Wk2[j*DD+d];
      acc[d] = fmaxf(acc[d], tt);
    }
  }
  float f0 = r1.y, f1 = r2.x, f2 = r2.y;
#pragma unroll
  for (int d = 0; d < DD; ++d) {
    float hg = fmaxf(f0*Wg[d] + f1*Wg[DD+d] + f2*Wg[2*DD+d], 0.f);
    acc[d] = fmaxf(acc[d], 0.f) + hg;          // final p_fea value
    out[O_PFEA + (size_t)i*DD + d] = acc[d];
  }
  // fused head MLP: out = relu(p_fea @ hW1) @ hW2
  float o[CC];
#pragma unroll
  for (int c = 0; c < CC; ++c) o[c] = 0.f;
  for (int d = 0; d < DD; ++d) {
    float t1 = 0.f;
#pragma unroll
    for (int j = 0; j < DD; ++j) t1 += acc[j]*hW1[j*DD+d];
    t1 = fmaxf(t1, 0.f);
#pragma unroll
    for (int c = 0; c < CC; ++c) o[c] += t1*hW2[d*CC+c];
  }
#pragma unroll
  for (int c = 0; c < CC; ++c) out[O_OUT + (size_t)i*CC + c] = o[c];
}

// ---------------- 6-NN cluster search (stable top-k) ----------------
__global__ __launch_bounds__(256) void k_knn(const float* __restrict__ xyz,
                      const float* __restrict__ cxyz,
                      const int* __restrict__ cidx, int* __restrict__ c2p,
                      float* __restrict__ out) {
  __shared__ float4 sc[MM];
  int i = blockIdx.x * 256 + threadIdx.x;
  int b = i >> 13;
  for (int m = threadIdx.x; m < MM; m += 256) {
    sc[m] = make_float4(cxyz[((size_t)b*MM+m)*3+0], cxyz[((size_t)b*MM+m)*3+1],
                        cxyz[((size_t)b*MM+m)*3+2], 0.f);
  }
  __syncthreads();
  float x = xyz[(size_t)i*3+0], y = xyz[(size_t)i*3+1], z = xyz[(size_t)i*3+2];
  float dv[KK]; int di[KK];
#pragma unroll
  for (int j = 0; j < KK; ++j) { dv[j] = 3.4e38f; di[j] = 0; }
  for (int m = 0; m < MM; ++m) {
    float4 c = sc[m];
    float dx = x - c.x, dy = y - c.y, dz = z - c.z;
    float d = __fadd_rn(__fadd_rn(__fmul_rn(dx,dx), __fmul_rn(dy,dy)), __fmul_rn(dz,dz));
    if (d < dv[KK-1]) {
      float v = d; int vi = m; bool ins = false;
#pragma unroll
      for (int j = 0; j < KK; ++j) {
        bool doit = ins || (v < dv[j]);   // strict <: stable top_k
        float tv = doit ? dv[j] : v; int ti = doit ? di[j] : vi;
        if (doit) { dv[j] = v; di[j] = vi; }
        v = tv; vi = ti; ins = doit;
      }
    }
  }
#pragma unroll
  for (int k = 0; k < KK; ++k) {
    c2p[(size_t)i*KK+k] = di[k];
    out[O_C2PA + (size_t)i*KK + k] = (float)di[k];
    out[O_C2P  + (size_t)i*KK + k] = (float)cidx[b*MM + di[k]];
  }
}

// ---------------- fused CSR build + pseudo-label: one block per batch ----------
__global__ __launch_bounds__(1024) void k_csr(const int* __restrict__ c2p,
                                              const int* __restrict__ label,
                                              int* __restrict__ cnt_g,
                                              int* __restrict__ offs_g,
                                              int* __restrict__ entries,
                                              float* __restrict__ out) {
  __shared__ int s_cnt[MM];
  __shared__ int s_off[MM];
  __shared__ int s_cur[MM];
  __shared__ int s_lab[MM*CC];
  int b = blockIdx.x, t = threadIdx.x;
  for (int i = t; i < MM; i += 1024) s_cnt[i] = 0;
  for (int i = t; i < MM*CC; i += 1024) s_lab[i] = 0;
  __syncthreads();
  const int* cb = c2p + (size_t)b*NN*KK;
  const int* lb = label + (size_t)b*NN;
  for (int n = t; n < NN; n += 1024) {
    int lab = lb[n];
#pragma unroll
    for (int k = 0; k < KK; ++k) {
      int m = cb[(size_t)n*KK+k];
      atomicAdd(&s_cnt[m], 1);
      atomicAdd(&s_lab[m*CC+lab], 1);
    }
  }
  __syncthreads();
  if (t < MM) s_off[t] = s_cnt[t];
  __syncthreads();
  for (int off = 1; off < MM; off <<= 1) {
    int v = 0;
    if (t < MM && t >= off) v = s_off[t-off];
    __syncthreads();
    if (t < MM && t >= off) s_off[t] += v;
    __syncthreads();
  }
  if (t < MM) {
    int ex = (t == 0) ? 0 : s_off[t-1];
    s_cur[t] = ex;
    offs_g[b*MM+t] = ex;
    cnt_g[b*MM+t] = s_cnt[t];
    int best = 0, bv = s_lab[t*CC];
#pragma unroll
    for (int c = 1; c < CC; ++c) { int v = s_lab[t*CC+c]; if (v > bv) { bv = v; best = c; } }
    out[O_PSLAB + b*MM + t] = (float)best;
#pragma unroll
    for (int c = 0; c < CC; ++c)
      out[O_PSOH + ((size_t)b*CC + c)*MM + t] = (c == best) ? 1.0f : 0.0f;
  }
  __syncthreads();
  for (int n = t; n < NN; n += 1024) {
#pragma unroll
    for (int k = 0; k < KK; ++k) {
      int m = cb[(size_t)n*KK+k];
      int pos = atomicAdd(&s_cur[m], 1);
      entries[(size_t)b*NN*KK + pos] = n*KK + k;
    }
  }
}

// ---------------- weighted scatter + fused sf@Wf1 (smeta) ----------------
__global__ __launch_bounds__(256, 1) void k_scat(const float* __restrict__ pfea,
                          const float* __restrict__ xyz,
                          const float* __restrict__ w,
                          const float* __restrict__ cxyz,
                          const float* __restrict__ onehot,
                          const int* __restrict__ entries, const int* __restrict__ offs,
                          const int* __restrict__ cnt,
                          const float* __restrict__ Wf1n,
                          float* __restrict__ sp_fea, float* __restrict__ sp_xyz,
                          float* __restrict__ sp_label, float* __restrict__ smeta,
                          float* __restrict__ out) {
  int bm = blockIdx.x;
  int b = bm >> 9, m = bm & (MM-1);
  int t = threadIdx.x;
  int wv = t >> 6, lane = t & 63;
  int base = b*NN*KK;
  int st = offs[bm], n_e = cnt[bm];
  __shared__ int   s_ent[1024];
  __shared__ float s_w[1024];
  __shared__ float s_f[4][DD], s_x[4][4], s_l[4][16], s_d[4];
  __shared__ float s_sf[DD], s_part[16][17];
  float acc = 0.f, accx = 0.f, accl = 0.f, den = 0.f;
  for (int c0 = 0; c0 < n_e; c0 += 1024) {
    int cn = min(1024, n_e - c0);
    __syncthreads();
    for (int e = t; e < cn; e += 256) {
      int ee = entries[base + st + c0 + e];
      s_ent[e] = ee;
      s_w[e] = w ? w[(size_t)base + ee] : 1.0f;
    }
    __syncthreads();
    for (int e = wv; e < cn; e += 4) {
      int ee = s_ent[e]; float ww = s_w[e];
      int n = ee / KK;
      acc += ww * pfea[((size_t)b*NN+n)*DD + lane];
      if (lane < 3) accx += ww * xyz[((size_t)b*NN+n)*3 + lane];
      if (onehot && lane < CC) accl += ww * onehot[((size_t)b*NN+n)*CC + lane];
      den += ww;
    }
  }
  s_f[wv][lane] = acc;
  if (lane < 4)  s_x[wv][lane] = (lane < 3) ? accx : 0.f;
  if (lane < 16) s_l[wv][lane] = (lane < CC) ? accl : 0.f;
  if (lane == 0) s_d[wv] = den;
  __syncthreads();
  if (wv == 0) {
    float A  = s_f[0][lane] + s_f[1][lane] + s_f[2][lane] + s_f[3][lane];
    float Dn = s_d[0] + s_d[1] + s_d[2] + s_d[3];
    float dv = w ? fmaxf(Dn, 1e-8f) : fmaxf(Dn, 1.0f);
    float sfv = A / dv;
    sp_fea[(size_t)bm*DD + lane] = sfv;
    s_sf[lane] = sfv;
    if (lane < 3) {
      float X = w ? (s_x[0][lane]+s_x[1][lane]+s_x[2][lane]+s_x[3][lane]) / dv
                  : cxyz[bm*3+lane];
      sp_xyz[bm*3+lane] = X;
      if (Wf1n) smeta[bm*20 + 16 + lane] = X;
    }
    if (onehot && lane < CC) {
      float L = (s_l[0][lane]+s_l[1][lane]+s_l[2][lane]+s_l[3][lane]) / fmaxf(Dn, 1e-8f);
      sp_label[(size_t)bm*CC + lane] = L;
      out[O_SPLABT + ((size_t)b*CC + lane)*MM + m] = L;
    }
  }
  if (Wf1n) {
    __syncthreads();
    int c = t & 15, part = t >> 4;
    float pr = 0.f;
#pragma unroll
    for (int q = 0; q < 4; ++q)
      pr += s_sf[part*4+q] * Wf1n[(part*4+q)*16 + c];
    s_part[part][c] = pr;
    __syncthreads();
    if (t < 16) {
      float sm = 0.f;
#pragma unroll
      for (int q = 0; q < 16; ++q) sm += s_part[q][t];
      smeta[bm*20 + t] = sm;
    }
  }
}

// ---------------- SLIC weight computation (one iteration) ----------------
__attribute__((amdgpu_waves_per_eu(3, 8)))
__global__ __launch_bounds__(256) void k_slicw(const float* __restrict__ pfea,
                        const float* __restrict__ xyz,
                        const float* __restrict__ smeta,
                        const int* __restrict__ c2p,
                        const float* __restrict__ Wf1, const float* __restrict__ Wf2,
                        const float* __restrict__ Wx1, const float* __restrict__ Wx2,
                        const float* __restrict__ Wm1, const float* __restrict__ Wm2,
                        float* __restrict__ wout, float* __restrict__ wout2) {
  int i = blockIdx.x*256 + threadIdx.x;
  int b = i >> 13;
  float pf[DD];
  const float4* pf4 = (const float4*)(pfea + (size_t)i*DD);
#pragma unroll
  for (int q = 0; q < DD/4; ++q) {
    float4 t = pf4[q];
    pf[q*4+0] = t.x; pf[q*4+1] = t.y; pf[q*4+2] = t.z; pf[q*4+3] = t.w;
  }
  float a[16];
#pragma unroll
  for (int c = 0; c < 16; ++c) a[c] = 0.f;
#pragma unroll
  for (int d = 0; d < DD; ++d) {
    float f = pf[d];
#pragma unroll
    for (int c = 0; c < 16; ++c) a[c] += f*Wm1[d*16+c];
  }
  float pm[16];
#pragma unroll
  for (int c2 = 0; c2 < 16; ++c2) {
    float t = 0.f;
#pragma unroll
    for (int c = 0; c < 16; ++c) t += fmaxf(a[c], 0.f)*Wm2[c*16+c2];
    pm[c2] = fmaxf(t, 0.f);
  }
  float pfd[16];
#pragma unroll
  for (int c = 0; c < 16; ++c) pfd[c] = 0.f;
#pragma unroll
  for (int d = 0; d < DD; ++d) {
    float f = pf[d];
#pragma unroll
    for (int c = 0; c < 16; ++c) pfd[c] += f*Wf1[d*16+c];
  }
  float x = xyz[(size_t)i*3+0], y = xyz[(size_t)i*3+1], z = xyz[(size_t)i*3+2];
  float lg[KK];
#pragma unroll 1
  for (int k = 0; k < KK; ++k) {
    int m = c2p[(size_t)i*KK+k];
    int bm = (b << 9) + m;
    const float4* mp = (const float4*)(smeta + (size_t)bm*20);
    float4 m0 = mp[0], m1 = mp[1], m2 = mp[2], m3 = mp[3], m4 = mp[4];
    float wa[16];
    wa[0]=m0.x-pfd[0];  wa[1]=m0.y-pfd[1];  wa[2]=m0.z-pfd[2];  wa[3]=m0.w-pfd[3];
    wa[4]=m1.x-pfd[4];  wa[5]=m1.y-pfd[5];  wa[6]=m1.z-pfd[6];  wa[7]=m1.w-pfd[7];
    wa[8]=m2.x-pfd[8];  wa[9]=m2.y-pfd[9];  wa[10]=m2.z-pfd[10]; wa[11]=m2.w-pfd[11];
    wa[12]=m3.x-pfd[12]; wa[13]=m3.y-pfd[13]; wa[14]=m3.z-pfd[14]; wa[15]=m3.w-pfd[15];
    float wf[16];
#pragma unroll
    for (int c2 = 0; c2 < 16; ++c2) {
      float t = 0.f;
#pragma unroll
      for (int c = 0; c < 16; ++c) t += fmaxf(wa[c], 0.f)*Wf2[c*16+c2];
      wf[c2] = fmaxf(t, 0.f);
    }
    float dx = m4.x - x, dy = m4.y - y, dz = m4.z - z;
    float ax[16];
#pragma unroll
    for (int c = 0; c < 16; ++c)
      ax[c] = fmaxf(dx*Wx1[c] + dy*Wx1[16+c] + dz*Wx1[32+c], 0.f);
    float lgk = 0.f;
#pragma unroll
    for (int c2 = 0; c2 < 16; ++c2) {
      float t = 0.f;
#pragma unroll
      for (int c = 0; c < 16; ++c) t += ax[c]*Wx2[c*16+c2];
      lgk += fmaxf(t, 0.f)*wf[c2]*pm[c2];
    }
    lg[k] = lgk;
  }
  float mx = lg[0];
#pragma unroll
  for (int k = 1; k < KK; ++k) mx = fmaxf(mx, lg[k]);
  float e[KK], s = 0.f;
#pragma unroll
  for (int k = 0; k < KK; ++k) { e[k] = expf(lg[k]-mx); s += e[k]; }
#pragma unroll
  for (int k = 0; k < KK; ++k) {
    float wv = e[k]/s;
    wout[(size_t)i*KK+k] = wv;
    if (wout2) wout2[(size_t)i*KK+k] = wv;
  }
}

// ---------------- per-point finalization ----------------
__global__ __launch_bounds__(256) void k_final(const float* __restrict__ sp_xyz, const float* __restrict__ sp_label,
                        const int* __restrict__ c2p, float* __restrict__ out) {
  int i = blockIdx.x*256 + threadIdx.x;
  int b = i >> 13;
  float w[KK]; int id[KK];
#pragma unroll
  for (int k = 0; k < KK; ++k) {
    w[k] = out[O_ASSO + (size_t)i*KK+k];
    id[k] = c2p[(size_t)i*KK+k];
  }
  int best = 0; float bv = w[0];
#pragma unroll
  for (int k = 1; k < KK; ++k) if (w[k] > bv) { bv = w[k]; best = k; }
  int sel = id[best];
#pragma unroll
  for (int c = 0; c < 3; ++c)
    out[O_RPXYZ + (size_t)i*3+c] = sp_xyz[((size_t)b*MM+sel)*3+c];
  float acc[CC];
#pragma unroll
  for (int c = 0; c < CC; ++c) acc[c] = 0.f;
#pragma unroll
  for (int k = 0; k < KK; ++k) {
    const float* sl = sp_label + ((size_t)b*MM + id[k])*CC;
    float ww = w[k];
#pragma unroll
    for (int c = 0; c < CC; ++c) acc[c] += ww*sl[c];
  }
#pragma unroll
  for (int c = 0; c < CC; ++c) out[O_RPLAB + (size_t)i*CC+c] = acc[c];
}

// ---------------- launcher ----------------
extern "C" void kernel_launch(void* const* d_in, const int* in_sizes, int n_in,
                              void* d_out, int out_size, void* d_ws, size_t ws_size,
                              hipStream_t stream) {
  const float* pc     = (const float*)d_in[0];
  const float* knn    = (const float*)d_in[1];
  const float* onehot = (const float*)d_in[2];
  const int*   label  = (const int*)d_in[3];
  const float* Wk1    = (const float*)d_in[4];
  const float* Wk2    = (const float*)d_in[5];
  const float* Wg     = (const float*)d_in[6];
  const float* hW1    = (const float*)d_in[7];
  const float* hW2    = (const float*)d_in[8];
  const float* Wf1    = (const float*)d_in[9];
  const float* Wf2    = (const float*)d_in[10];
  const float* Wx1    = (const float*)d_in[11];
  const float* Wx2    = (const float*)d_in[12];
  const float* Wm1    = (const float*)d_in[13];
  const float* Wm2    = (const float*)d_in[14];
  float* out = (float*)d_out;

  float* wsf = (float*)d_ws;
  size_t o = 0;
  float* xyz     = wsf + o; o += (size_t)BB*NN*3;
  float* cxyz    = wsf + o; o += (size_t)BB*MM*3;
  int*   cidx    = (int*)(wsf + o); o += BB*MM;
  int*   c2p     = (int*)(wsf + o); o += (size_t)BB*NN*KK;
  int*   cnt     = (int*)(wsf + o); o += BB*MM;
  int*   offs    = (int*)(wsf + o); o += BB*MM;
  int*   entries = (int*)(wsf + o); o += (size_t)BB*NN*KK;
  float* sp_fea  = wsf + o; o += (size_t)BB*MM*DD;
  float* sp_xyz  = wsf + o; o += (size_t)BB*MM*3;
  float* sp_label= wsf + o; o += (size_t)BB*MM*CC;
  float* smeta   = wsf + o; o += (size_t)BB*MM*20;

  k_fps  <<<BB, 512, 0, stream>>>(pc, cidx, cxyz, out);
  k_pfea <<<BB*NN/256, 256, 0, stream>>>(pc, knn, Wk1, Wk2, Wg, hW1, hW2, xyz, out);
  k_knn  <<<BB*NN/256, 256, 0, stream>>>(xyz, cxyz, cidx, c2p, out);
  k_csr  <<<BB, 1024, 0, stream>>>(c2p, label, cnt, offs, entries, out);
  // init: sp_fea = mean, sp_xyz = cluster_xyz, smeta for layer 0
  k_scat<<<BB*MM, 256, 0, stream>>>(out + O_PFEA, xyz, nullptr, cxyz, nullptr,
      entries, offs, cnt, Wf1 /*layer0*/, sp_fea, sp_xyz, nullptr, smeta, out);
  for (int l = 0; l < 4; ++l) {
    k_slicw<<<BB*NN/256, 256, 0, stream>>>(out + O_PFEA, xyz, smeta, c2p,
        Wf1 + l*DD*16, Wf2 + l*256, Wx1 + l*48, Wx2 + l*256,
        Wm1 + l*DD*16, Wm2 + l*256,
        out + O_ASSO, (l == 3) ? (out + O_FDIST) : nullptr);
    k_scat<<<BB*MM, 256, 0, stream>>>(out + O_PFEA, xyz, out + O_ASSO, cxyz,
        (l == 3) ? onehot : nullptr, entries, offs, cnt,
        (l < 3) ? (Wf1 + (l+1)*DD*16) : nullptr,
        sp_fea, sp_xyz, sp_label, smeta, out);
  }
  k_final<<<BB*NN/256, 256, 0, stream>>>(sp_xyz, sp_label, c2p, out);
}

// Round 9
// 2443.392 us; speedup vs baseline: 1.5707x; 1.5707x over previous
//
#include <hip/hip_runtime.h>

#define BB 8
#define NN 8192
#define MM 512
#define KK 6
#define NSAMP 16
#define CC 13
#define DD 64

typedef float v2f __attribute__((ext_vector_type(2)));

// ---- output slot offsets (in floats) ----
#define O_ASSO   0u          // final_asso      (B,N,K)  393216
#define O_CIDX   393216u     // cluster_idx     (B,M)    4096
#define O_C2P    397312u     // c2p_idx         (B,N,K)  393216
#define O_C2PA   790528u     // c2p_idx_abs     (B,N,K)  393216
#define O_OUT    1183744u    // out             (B,N,C)  851968
#define O_RPXYZ  2035712u    // re_p_xyz        (B,N,3)  196608
#define O_RPLAB  2232320u    // re_p_label      (B,N,C)  851968
#define O_FDIST  3084288u    // fea_dist        (B,N,K)  393216
#define O_PFEA   3477504u    // p_fea           (B,N,D)  4194304
#define O_SPLABT 7671808u    // sp_label^T      (B,C,M)  53248
#define O_PSLAB  7725056u    // sp_pseudo_lab   (B,M)    4096
#define O_PSOH   7729152u    // sp_pseudo_oh    (B,C,M)  53248

// ---- DPP wave64 max-reduce of a u64 key; valid result in lane 63 ----
__device__ __forceinline__ unsigned long long dpp_max_u64(unsigned long long k) {
  int lo = (int)(unsigned)(k & 0xFFFFFFFFull);
  int hi = (int)(unsigned)(k >> 32);
#define DPP_STEP(ctrl)                                                         \
  {                                                                            \
    int nlo = __builtin_amdgcn_update_dpp(0, lo, ctrl, 0xf, 0xf, true);        \
    int nhi = __builtin_amdgcn_update_dpp(0, hi, ctrl, 0xf, 0xf, true);        \
    unsigned long long nk =                                                    \
        ((unsigned long long)(unsigned)nhi << 32) | (unsigned)nlo;             \
    unsigned long long ck =                                                    \
        ((unsigned long long)(unsigned)hi << 32) | (unsigned)lo;               \
    if (nk > ck) { lo = nlo; hi = nhi; }                                       \
  }
  DPP_STEP(0x111)  // row_shr:1
  DPP_STEP(0x112)  // row_shr:2
  DPP_STEP(0x114)  // row_shr:4
  DPP_STEP(0x118)  // row_shr:8  -> lane15/31/47/63 hold row maxima
  DPP_STEP(0x142)  // row_bcast:15 -> lane31=max(r0,r1), lane63=max(r2,r3)
  DPP_STEP(0x143)  // row_bcast:31 -> lane63=max(all)
#undef DPP_STEP
  return ((unsigned long long)(unsigned)hi << 32) | (unsigned)lo;
}

// ======== uber: FPS (blocks 0..7) + pack+p_fea+head (blocks 8..135), 512 thr =====
// amdgpu_waves_per_eu(1,2): honored range -> 256-VGPR budget at 2 waves/EU.
// FPS branch ~90 live regs (8x v2f point arrays), pfea branch ~120 -> no spill.
__attribute__((amdgpu_waves_per_eu(1, 2)))
__global__ __launch_bounds__(512) void k_uber(const float* __restrict__ pc,
                                              const float* __restrict__ knn,
                                              const float* __restrict__ Wk1,
                                              const float* __restrict__ Wk2,
                                              const float* __restrict__ Wg,
                                              const float* __restrict__ hW1,
                                              const float* __restrict__ hW2,
                                              float* __restrict__ xyz,
                                              int* __restrict__ cidx,
                                              float* __restrict__ cxyz,
                                              float* __restrict__ out) {
#pragma clang fp contract(off)
  __shared__ float sx[NN], sy[NN], sz[NN];
  __shared__ unsigned long long s_best[2][8];
  __shared__ int   s_pidx[MM];
  __shared__ float s_px[MM], s_py[MM], s_pz[MM];
  const int t = threadIdx.x;
  if (blockIdx.x < 8) {
    // ---------- FPS: 512 threads, 16 pts/thread as 8 v2f stream-pairs ----------
    // streams A: p=t+2j*512, B: p=t+(2j+1)*512 -> v_pk_{add,mul}_f32 core.
    // contract(off) keeps numpy-exact separate mul+add rounding.
    const int b = blockIdx.x;
    const float* xb = pc + (size_t)b * NN * 6;
    v2f px[8], py[8], pz[8], dist[8];
#pragma unroll
    for (int j = 0; j < 8; ++j) {
      int p0 = t + (2*j)*512, p1 = t + (2*j+1)*512;
      float X0 = xb[(size_t)p0*6+0], Y0 = xb[(size_t)p0*6+1], Z0 = xb[(size_t)p0*6+2];
      float X1 = xb[(size_t)p1*6+0], Y1 = xb[(size_t)p1*6+1], Z1 = xb[(size_t)p1*6+2];
      px[j] = (v2f){X0, X1}; py[j] = (v2f){Y0, Y1}; pz[j] = (v2f){Z0, Z1};
      dist[j] = (v2f){1e10f, 1e10f};
      sx[p0] = X0; sy[p0] = Y0; sz[p0] = Z0;
      sx[p1] = X1; sy[p1] = Y1; sz[p1] = Z1;
    }
    __syncthreads();
    float lx = sx[0], ly = sy[0], lz = sz[0];
    if (t == 0) { s_pidx[0] = 0; s_px[0] = lx; s_py[0] = ly; s_pz[0] = lz; }
    const int lane = t & 63, wave = t >> 6;
    for (int step = 1; step < MM; ++step) {
      float bvA = -1.0f, bvB = -1.0f; int bpA = 0, bpB = 0;
#pragma unroll
      for (int j = 0; j < 8; ++j) {
        v2f dx = px[j] - lx, dy = py[j] - ly, dz = pz[j] - lz;
        v2f d = (dx*dx + dy*dy) + dz*dz;       // contract(off): exact numpy order
        v2f nd = __builtin_elementwise_min(dist[j], d);
        dist[j] = nd;
        float nA = nd.x, nB = nd.y;
        if (nA > bvA) { bvA = nA; bpA = t + (2*j)*512; }    // stream A: p ascending
        if (nB > bvB) { bvB = nB; bpB = t + (2*j+1)*512; }  // stream B: p ascending
      }
      // exact tie handling across streams via packed keys (tie -> smaller p)
      unsigned long long kA = ((unsigned long long)__float_as_uint(bvA) << 32)
                            | (unsigned)(0xFFFFFFFFu - (unsigned)bpA);
      unsigned long long kB = ((unsigned long long)__float_as_uint(bvB) << 32)
                            | (unsigned)(0xFFFFFFFFu - (unsigned)bpB);
      unsigned long long key = (kB > kA) ? kB : kA;
      key = dpp_max_u64(key);              // VALU-only wave reduce; lane 63 valid
      if (lane == 63) s_best[step & 1][wave] = key;
      __syncthreads();                     // single barrier (parity dbuf)
      const ulonglong2* sb = (const ulonglong2*)s_best[step & 1];
      ulonglong2 q0 = sb[0], q1 = sb[1], q2 = sb[2], q3 = sb[3];
      unsigned long long kk = q0.x;
      if (q0.y > kk) kk = q0.y;
      if (q1.x > kk) kk = q1.x;
      if (q1.y > kk) kk = q1.y;
      if (q2.x > kk) kk = q2.x;
      if (q2.y > kk) kk = q2.y;
      if (q3.x > kk) kk = q3.x;
      if (q3.y > kk) kk = q3.y;
      int p = (int)(0xFFFFFFFFu - (unsigned)(kk & 0xFFFFFFFFull));
      lx = sx[p]; ly = sy[p]; lz = sz[p];  // LDS broadcast
      if (t == 0) {                        // LDS staging only
        s_pidx[step] = p;
        s_px[step] = lx; s_py[step] = ly; s_pz[step] = lz;
      }
    }
    __syncthreads();
    // coalesced epilogue: write all selected indices/coords once
    if (t < MM) {
      int p = s_pidx[t];
      cidx[b*MM + t] = p;
      out[O_CIDX + b*MM + t] = (float)p;
      cxyz[((size_t)b*MM + t)*3+0] = s_px[t];
      cxyz[((size_t)b*MM + t)*3+1] = s_py[t];
      cxyz[((size_t)b*MM + t)*3+2] = s_pz[t];
    }
  } else {
    // ---------- pack + p_fea + head: 1 point/thread ----------
    int i = (blockIdx.x - 8) * 512 + t;
    const float2* pr = (const float2*)(pc + (size_t)i*6);
    float2 r0 = pr[0], r1 = pr[1], r2 = pr[2];
    float* xo = xyz + (size_t)i*3;
    xo[0] = r0.x; xo[1] = r0.y; xo[2] = r1.x;
    float acc[DD];
#pragma unroll
    for (int d = 0; d < DD; ++d) acc[d] = -3.4e38f;
    const float* kp = knn + (size_t)i * NSAMP * 2;
    for (int s = 0; s < NSAMP; ++s) {
      float u = kp[s*2+0], v2 = kp[s*2+1];
      float h1[32];
#pragma unroll
      for (int j = 0; j < 32; ++j) h1[j] = fmaxf(u*Wk1[j] + v2*Wk1[32+j], 0.f);
#pragma unroll
      for (int d = 0; d < DD; ++d) {
        float tt = 0.f;
#pragma unroll
        for (int j = 0; j < 32; ++j) tt += h1[j]*Wk2[j*DD+d];
        acc[d] = fmaxf(acc[d], tt);
      }
    }
    float f0 = r1.y, f1 = r2.x, f2 = r2.y;
#pragma unroll
    for (int d = 0; d < DD; ++d) {
      float hg = fmaxf(f0*Wg[d] + f1*Wg[DD+d] + f2*Wg[2*DD+d], 0.f);
      acc[d] = fmaxf(acc[d], 0.f) + hg;          // final p_fea value
      out[O_PFEA + (size_t)i*DD + d] = acc[d];
    }
    // fused head MLP: out = relu(p_fea @ hW1) @ hW2
    float o[CC];
#pragma unroll
    for (int c = 0; c < CC; ++c) o[c] = 0.f;
    for (int d = 0; d < DD; ++d) {
      float t1 = 0.f;
#pragma unroll
      for (int j = 0; j < DD; ++j) t1 += acc[j]*hW1[j*DD+d];
      t1 = fmaxf(t1, 0.f);
#pragma unroll
      for (int c = 0; c < CC; ++c) o[c] += t1*hW2[d*CC+c];
    }
#pragma unroll
    for (int c = 0; c < CC; ++c) out[O_OUT + (size_t)i*CC + c] = o[c];
  }
}

// ---------------- 6-NN cluster search (stable top-k) ----------------
__global__ __launch_bounds__(256) void k_knn(const float* __restrict__ xyz,
                      const float* __restrict__ cxyz,
                      const int* __restrict__ cidx, int* __restrict__ c2p,
                      float* __restrict__ out) {
  __shared__ float4 sc[MM];
  int i = blockIdx.x * 256 + threadIdx.x;
  int b = i >> 13;
  for (int m = threadIdx.x; m < MM; m += 256) {
    sc[m] = make_float4(cxyz[((size_t)b*MM+m)*3+0], cxyz[((size_t)b*MM+m)*3+1],
                        cxyz[((size_t)b*MM+m)*3+2], 0.f);
  }
  __syncthreads();
  float x = xyz[(size_t)i*3+0], y = xyz[(size_t)i*3+1], z = xyz[(size_t)i*3+2];
  float dv[KK]; int di[KK];
#pragma unroll
  for (int j = 0; j < KK; ++j) { dv[j] = 3.4e38f; di[j] = 0; }
  for (int m = 0; m < MM; ++m) {
    float4 c = sc[m];
    float dx = x - c.x, dy = y - c.y, dz = z - c.z;
    float d = __fadd_rn(__fadd_rn(__fmul_rn(dx,dx), __fmul_rn(dy,dy)), __fmul_rn(dz,dz));
    if (d < dv[KK-1]) {
      float v = d; int vi = m; bool ins = false;
#pragma unroll
      for (int j = 0; j < KK; ++j) {
        bool doit = ins || (v < dv[j]);   // strict <: stable top_k
        float tv = doit ? dv[j] : v; int ti = doit ? di[j] : vi;
        if (doit) { dv[j] = v; di[j] = vi; }
        v = tv; vi = ti; ins = doit;
      }
    }
  }
#pragma unroll
  for (int k = 0; k < KK; ++k) {
    c2p[(size_t)i*KK+k] = di[k];
    out[O_C2PA + (size_t)i*KK + k] = (float)di[k];
    out[O_C2P  + (size_t)i*KK + k] = (float)cidx[b*MM + di[k]];
  }
}

// ---------------- fused CSR build + pseudo-label: one block per batch ----------
__global__ __launch_bounds__(1024) void k_csr(const int* __restrict__ c2p,
                                              const int* __restrict__ label,
                                              int* __restrict__ cnt_g,
                                              int* __restrict__ offs_g,
                                              int* __restrict__ entries,
                                              float* __restrict__ out) {
  __shared__ int s_cnt[MM];
  __shared__ int s_off[MM];
  __shared__ int s_cur[MM];
  __shared__ int s_lab[MM*CC];
  int b = blockIdx.x, t = threadIdx.x;
  for (int i = t; i < MM; i += 1024) s_cnt[i] = 0;
  for (int i = t; i < MM*CC; i += 1024) s_lab[i] = 0;
  __syncthreads();
  const int* cb = c2p + (size_t)b*NN*KK;
  const int* lb = label + (size_t)b*NN;
  for (int n = t; n < NN; n += 1024) {
    int lab = lb[n];
#pragma unroll
    for (int k = 0; k < KK; ++k) {
      int m = cb[(size_t)n*KK+k];
      atomicAdd(&s_cnt[m], 1);
      atomicAdd(&s_lab[m*CC+lab], 1);
    }
  }
  __syncthreads();
  if (t < MM) s_off[t] = s_cnt[t];
  __syncthreads();
  for (int off = 1; off < MM; off <<= 1) {
    int v = 0;
    if (t < MM && t >= off) v = s_off[t-off];
    __syncthreads();
    if (t < MM && t >= off) s_off[t] += v;
    __syncthreads();
  }
  if (t < MM) {
    int ex = (t == 0) ? 0 : s_off[t-1];
    s_cur[t] = ex;
    offs_g[b*MM+t] = ex;
    cnt_g[b*MM+t] = s_cnt[t];
    int best = 0, bv = s_lab[t*CC];
#pragma unroll
    for (int c = 1; c < CC; ++c) { int v = s_lab[t*CC+c]; if (v > bv) { bv = v; best = c; } }
    out[O_PSLAB + b*MM + t] = (float)best;
#pragma unroll
    for (int c = 0; c < CC; ++c)
      out[O_PSOH + ((size_t)b*CC + c)*MM + t] = (c == best) ? 1.0f : 0.0f;
  }
  __syncthreads();
  for (int n = t; n < NN; n += 1024) {
#pragma unroll
    for (int k = 0; k < KK; ++k) {
      int m = cb[(size_t)n*KK+k];
      int pos = atomicAdd(&s_cur[m], 1);
      entries[(size_t)b*NN*KK + pos] = n*KK + k;
    }
  }
}

// ---------------- weighted scatter + fused sf@Wf1 (smeta) ----------------
__global__ __launch_bounds__(256, 1) void k_scat(const float* __restrict__ pfea,
                          const float* __restrict__ xyz,
                          const float* __restrict__ w,
                          const float* __restrict__ cxyz,
                          const float* __restrict__ onehot,
                          const int* __restrict__ entries, const int* __restrict__ offs,
                          const int* __restrict__ cnt,
                          const float* __restrict__ Wf1n,
                          float* __restrict__ sp_fea, float* __restrict__ sp_xyz,
                          float* __restrict__ sp_label, float* __restrict__ smeta,
                          float* __restrict__ out) {
  int bm = blockIdx.x;
  int b = bm >> 9, m = bm & (MM-1);
  int t = threadIdx.x;
  int wv = t >> 6, lane = t & 63;
  int base = b*NN*KK;
  int st = offs[bm], n_e = cnt[bm];
  __shared__ int   s_ent[1024];
  __shared__ float s_w[1024];
  __shared__ float s_f[4][DD], s_x[4][4], s_l[4][16], s_d[4];
  __shared__ float s_sf[DD], s_part[16][17];
  float acc = 0.f, accx = 0.f, accl = 0.f, den = 0.f;
  for (int c0 = 0; c0 < n_e; c0 += 1024) {
    int cn = min(1024, n_e - c0);
    __syncthreads();
    for (int e = t; e < cn; e += 256) {
      int ee = entries[base + st + c0 + e];
      s_ent[e] = ee;
      s_w[e] = w ? w[(size_t)base + ee] : 1.0f;
    }
    __syncthreads();
    for (int e = wv; e < cn; e += 4) {
      int ee = s_ent[e]; float ww = s_w[e];
      int n = ee / KK;
      acc += ww * pfea[((size_t)b*NN+n)*DD + lane];
      if (lane < 3) accx += ww * xyz[((size_t)b*NN+n)*3 + lane];
      if (onehot && lane < CC) accl += ww * onehot[((size_t)b*NN+n)*CC + lane];
      den += ww;
    }
  }
  s_f[wv][lane] = acc;
  if (lane < 4)  s_x[wv][lane] = (lane < 3) ? accx : 0.f;
  if (lane < 16) s_l[wv][lane] = (lane < CC) ? accl : 0.f;
  if (lane == 0) s_d[wv] = den;
  __syncthreads();
  if (wv == 0) {
    float A  = s_f[0][lane] + s_f[1][lane] + s_f[2][lane] + s_f[3][lane];
    float Dn = s_d[0] + s_d[1] + s_d[2] + s_d[3];
    float dv = w ? fmaxf(Dn, 1e-8f) : fmaxf(Dn, 1.0f);
    float sfv = A / dv;
    sp_fea[(size_t)bm*DD + lane] = sfv;
    s_sf[lane] = sfv;
    if (lane < 3) {
      float X = w ? (s_x[0][lane]+s_x[1][lane]+s_x[2][lane]+s_x[3][lane]) / dv
                  : cxyz[bm*3+lane];
      sp_xyz[bm*3+lane] = X;
      if (Wf1n) smeta[bm*20 + 16 + lane] = X;
    }
    if (onehot && lane < CC) {
      float L = (s_l[0][lane]+s_l[1][lane]+s_l[2][lane]+s_l[3][lane]) / fmaxf(Dn, 1e-8f);
      sp_label[(size_t)bm*CC + lane] = L;
      out[O_SPLABT + ((size_t)b*CC + lane)*MM + m] = L;
    }
  }
  if (Wf1n) {
    __syncthreads();
    int c = t & 15, part = t >> 4;
    float pr = 0.f;
#pragma unroll
    for (int q = 0; q < 4; ++q)
      pr += s_sf[part*4+q] * Wf1n[(part*4+q)*16 + c];
    s_part[part][c] = pr;
    __syncthreads();
    if (t < 16) {
      float sm = 0.f;
#pragma unroll
      for (int q = 0; q < 16; ++q) sm += s_part[q][t];
      smeta[bm*20 + t] = sm;
    }
  }
}

// ---------------- SLIC weight computation (one iteration) ----------------
// (1,2): honored range -> 256-VGPR budget; ~150 live regs stay in registers.
__attribute__((amdgpu_waves_per_eu(1, 2)))
__global__ __launch_bounds__(256) void k_slicw(const float* __restrict__ pfea,
                        const float* __restrict__ xyz,
                        const float* __restrict__ smeta,
                        const int* __restrict__ c2p,
                        const float* __restrict__ Wf1, const float* __restrict__ Wf2,
                        const float* __restrict__ Wx1, const float* __restrict__ Wx2,
                        const float* __restrict__ Wm1, const float* __restrict__ Wm2,
                        float* __restrict__ wout, float* __restrict__ wout2) {
  int i = blockIdx.x*256 + threadIdx.x;
  int b = i >> 13;
  float pf[DD];
  const float4* pf4 = (const float4*)(pfea + (size_t)i*DD);
#pragma unroll
  for (int q = 0; q < DD/4; ++q) {
    float4 t = pf4[q];
    pf[q*4+0] = t.x; pf[q*4+1] = t.y; pf[q*4+2] = t.z; pf[q*4+3] = t.w;
  }
  float a[16];
#pragma unroll
  for (int c = 0; c < 16; ++c) a[c] = 0.f;
#pragma unroll
  for (int d = 0; d < DD; ++d) {
    float f = pf[d];
#pragma unroll
    for (int c = 0; c < 16; ++c) a[c] += f*Wm1[d*16+c];
  }
  float pm[16];
#pragma unroll
  for (int c2 = 0; c2 < 16; ++c2) {
    float t = 0.f;
#pragma unroll
    for (int c = 0; c < 16; ++c) t += fmaxf(a[c], 0.f)*Wm2[c*16+c2];
    pm[c2] = fmaxf(t, 0.f);
  }
  float pfd[16];
#pragma unroll
  for (int c = 0; c < 16; ++c) pfd[c] = 0.f;
#pragma unroll
  for (int d = 0; d < DD; ++d) {
    float f = pf[d];
#pragma unroll
    for (int c = 0; c < 16; ++c) pfd[c] += f*Wf1[d*16+c];
  }
  float x = xyz[(size_t)i*3+0], y = xyz[(size_t)i*3+1], z = xyz[(size_t)i*3+2];
  float lg[KK];
#pragma unroll 1
  for (int k = 0; k < KK; ++k) {
    int m = c2p[(size_t)i*KK+k];
    int bm = (b << 9) + m;
    const float4* mp = (const float4*)(smeta + (size_t)bm*20);
    float4 m0 = mp[0], m1 = mp[1], m2 = mp[2], m3 = mp[3], m4 = mp[4];
    float wa[16];
    wa[0]=m0.x-pfd[0];  wa[1]=m0.y-pfd[1];  wa[2]=m0.z-pfd[2];  wa[3]=m0.w-pfd[3];
    wa[4]=m1.x-pfd[4];  wa[5]=m1.y-pfd[5];  wa[6]=m1.z-pfd[6];  wa[7]=m1.w-pfd[7];
    wa[8]=m2.x-pfd[8];  wa[9]=m2.y-pfd[9];  wa[10]=m2.z-pfd[10]; wa[11]=m2.w-pfd[11];
    wa[12]=m3.x-pfd[12]; wa[13]=m3.y-pfd[13]; wa[14]=m3.z-pfd[14]; wa[15]=m3.w-pfd[15];
    float wf[16];
#pragma unroll
    for (int c2 = 0; c2 < 16; ++c2) {
      float t = 0.f;
#pragma unroll
      for (int c = 0; c < 16; ++c) t += fmaxf(wa[c], 0.f)*Wf2[c*16+c2];
      wf[c2] = fmaxf(t, 0.f);
    }
    float dx = m4.x - x, dy = m4.y - y, dz = m4.z - z;
    float ax[16];
#pragma unroll
    for (int c = 0; c < 16; ++c)
      ax[c] = fmaxf(dx*Wx1[c] + dy*Wx1[16+c] + dz*Wx1[32+c], 0.f);
    float lgk = 0.f;
#pragma unroll
    for (int c2 = 0; c2 < 16; ++c2) {
      float t = 0.f;
#pragma unroll
      for (int c = 0; c < 16; ++c) t += ax[c]*Wx2[c*16+c2];
      lgk += fmaxf(t, 0.f)*wf[c2]*pm[c2];
    }
    lg[k] = lgk;
  }
  float mx = lg[0];
#pragma unroll
  for (int k = 1; k < KK; ++k) mx = fmaxf(mx, lg[k]);
  float e[KK], s = 0.f;
#pragma unroll
  for (int k = 0; k < KK; ++k) { e[k] = expf(lg[k]-mx); s += e[k]; }
#pragma unroll
  for (int k = 0; k < KK; ++k) {
    float wv = e[k]/s;
    wout[(size_t)i*KK+k] = wv;
    if (wout2) wout2[(size_t)i*KK+k] = wv;
  }
}

// ---------------- per-point finalization ----------------
__global__ __launch_bounds__(256) void k_final(const float* __restrict__ sp_xyz, const float* __restrict__ sp_label,
                        const int* __restrict__ c2p, float* __restrict__ out) {
  int i = blockIdx.x*256 + threadIdx.x;
  int b = i >> 13;
  float w[KK]; int id[KK];
#pragma unroll
  for (int k = 0; k < KK; ++k) {
    w[k] = out[O_ASSO + (size_t)i*KK+k];
    id[k] = c2p[(size_t)i*KK+k];
  }
  int best = 0; float bv = w[0];
#pragma unroll
  for (int k = 1; k < KK; ++k) if (w[k] > bv) { bv = w[k]; best = k; }
  int sel = id[best];
#pragma unroll
  for (int c = 0; c < 3; ++c)
    out[O_RPXYZ + (size_t)i*3+c] = sp_xyz[((size_t)b*MM+sel)*3+c];
  float acc[CC];
#pragma unroll
  for (int c = 0; c < CC; ++c) acc[c] = 0.f;
#pragma unroll
  for (int k = 0; k < KK; ++k) {
    const float* sl = sp_label + ((size_t)b*MM + id[k])*CC;
    float ww = w[k];
#pragma unroll
    for (int c = 0; c < CC; ++c) acc[c] += ww*sl[c];
  }
#pragma unroll
  for (int c = 0; c < CC; ++c) out[O_RPLAB + (size_t)i*CC+c] = acc[c];
}

// ---------------- launcher ----------------
extern "C" void kernel_launch(void* const* d_in, const int* in_sizes, int n_in,
                              void* d_out, int out_size, void* d_ws, size_t ws_size,
                              hipStream_t stream) {
  const float* pc     = (const float*)d_in[0];
  const float* knn    = (const float*)d_in[1];
  const float* onehot = (const float*)d_in[2];
  const int*   label  = (const int*)d_in[3];
  const float* Wk1    = (const float*)d_in[4];
  const float* Wk2    = (const float*)d_in[5];
  const float* Wg     = (const float*)d_in[6];
  const float* hW1    = (const float*)d_in[7];
  const float* hW2    = (const float*)d_in[8];
  const float* Wf1    = (const float*)d_in[9];
  const float* Wf2    = (const float*)d_in[10];
  const float* Wx1    = (const float*)d_in[11];
  const float* Wx2    = (const float*)d_in[12];
  const float* Wm1    = (const float*)d_in[13];
  const float* Wm2    = (const float*)d_in[14];
  float* out = (float*)d_out;

  float* wsf = (float*)d_ws;
  size_t o = 0;
  float* xyz     = wsf + o; o += (size_t)BB*NN*3;
  float* cxyz    = wsf + o; o += (size_t)BB*MM*3;
  int*   cidx    = (int*)(wsf + o); o += BB*MM;
  int*   c2p     = (int*)(wsf + o); o += (size_t)BB*NN*KK;
  int*   cnt     = (int*)(wsf + o); o += BB*MM;
  int*   offs    = (int*)(wsf + o); o += BB*MM;
  int*   entries = (int*)(wsf + o); o += (size_t)BB*NN*KK;
  float* sp_fea  = wsf + o; o += (size_t)BB*MM*DD;
  float* sp_xyz  = wsf + o; o += (size_t)BB*MM*3;
  float* sp_label= wsf + o; o += (size_t)BB*MM*CC;
  float* smeta   = wsf + o; o += (size_t)BB*MM*20;

  k_uber <<<8 + BB*NN/512, 512, 0, stream>>>(pc, knn, Wk1, Wk2, Wg, hW1, hW2,
                                             xyz, cidx, cxyz, out);
  k_knn  <<<BB*NN/256, 256, 0, stream>>>(xyz, cxyz, cidx, c2p, out);
  k_csr  <<<BB, 1024, 0, stream>>>(c2p, label, cnt, offs, entries, out);
  // init: sp_fea = mean, sp_xyz = cluster_xyz, smeta for layer 0
  k_scat<<<BB*MM, 256, 0, stream>>>(out + O_PFEA, xyz, nullptr, cxyz, nullptr,
      entries, offs, cnt, Wf1 /*layer0*/, sp_fea, sp_xyz, nullptr, smeta, out);
  for (int l = 0; l < 4; ++l) {
    k_slicw<<<BB*NN/256, 256, 0, stream>>>(out + O_PFEA, xyz, smeta, c2p,
        Wf1 + l*DD*16, Wf2 + l*256, Wx1 + l*48, Wx2 + l*256,
        Wm1 + l*DD*16, Wm2 + l*256,
        out + O_ASSO, (l == 3) ? (out + O_FDIST) : nullptr);
    k_scat<<<BB*MM, 256, 0, stream>>>(out + O_PFEA, xyz, out + O_ASSO, cxyz,
        (l == 3) ? onehot : nullptr, entries, offs, cnt,
        (l < 3) ? (Wf1 + (l+1)*DD*16) : nullptr,
        sp_fea, sp_xyz, sp_label, smeta, out);
  }
  k_final<<<BB*NN/256, 256, 0, stream>>>(sp_xyz, sp_label, c2p, out);
}

// Round 10
// 1566.727 us; speedup vs baseline: 2.4496x; 1.5596x over previous
//
#include <hip/hip_runtime.h>

#define BB 8
#define NN 8192
#define MM 512
#define KK 6
#define NSAMP 16
#define CC 13
#define DD 64

typedef float v2f __attribute__((ext_vector_type(2)));

// ---- output slot offsets (in floats) ----
#define O_ASSO   0u          // final_asso      (B,N,K)  393216
#define O_CIDX   393216u     // cluster_idx     (B,M)    4096
#define O_C2P    397312u     // c2p_idx         (B,N,K)  393216
#define O_C2PA   790528u     // c2p_idx_abs     (B,N,K)  393216
#define O_OUT    1183744u    // out             (B,N,C)  851968
#define O_RPXYZ  2035712u    // re_p_xyz        (B,N,3)  196608
#define O_RPLAB  2232320u    // re_p_label      (B,N,C)  851968
#define O_FDIST  3084288u    // fea_dist        (B,N,K)  393216
#define O_PFEA   3477504u    // p_fea           (B,N,D)  4194304
#define O_SPLABT 7671808u    // sp_label^T      (B,C,M)  53248
#define O_PSLAB  7725056u    // sp_pseudo_lab   (B,M)    4096
#define O_PSOH   7729152u    // sp_pseudo_oh    (B,C,M)  53248

// ---- DPP wave64 max-reduce of a u64 key; valid result in lane 63 ----
__device__ __forceinline__ unsigned long long dpp_max_u64(unsigned long long k) {
  int lo = (int)(unsigned)(k & 0xFFFFFFFFull);
  int hi = (int)(unsigned)(k >> 32);
#define DPP_STEP(ctrl)                                                         \
  {                                                                            \
    int nlo = __builtin_amdgcn_update_dpp(0, lo, ctrl, 0xf, 0xf, true);        \
    int nhi = __builtin_amdgcn_update_dpp(0, hi, ctrl, 0xf, 0xf, true);        \
    unsigned long long nk =                                                    \
        ((unsigned long long)(unsigned)nhi << 32) | (unsigned)nlo;             \
    unsigned long long ck =                                                    \
        ((unsigned long long)(unsigned)hi << 32) | (unsigned)lo;               \
    if (nk > ck) { lo = nlo; hi = nhi; }                                       \
  }
  DPP_STEP(0x111)  // row_shr:1
  DPP_STEP(0x112)  // row_shr:2
  DPP_STEP(0x114)  // row_shr:4
  DPP_STEP(0x118)  // row_shr:8  -> lane15/31/47/63 hold row maxima
  DPP_STEP(0x142)  // row_bcast:15 -> lane31=max(r0,r1), lane63=max(r2,r3)
  DPP_STEP(0x143)  // row_bcast:31 -> lane63=max(all)
#undef DPP_STEP
  return ((unsigned long long)(unsigned)hi << 32) | (unsigned)lo;
}

// ================= FPS: one 512-thread block per batch, 16 pts/thread ============
// pk-math core: points in v2f stream-pairs (A: p=t+2j*512, B: p=t+(2j+1)*512) so
// the distance core lowers to v_pk_{add,mul}_f32 (2x VALU). contract(off) keeps
// numpy-exact separate mul+add rounding; per-stream argmax + u64-key merge keeps
// the first-max (smallest index) tie rule bit-exact (validated R8/R9: absmax
// identical to scalar version). LDS-staged outputs, coalesced epilogue.
__global__ __launch_bounds__(512, 1) void k_fps(const float* __restrict__ pc,
                                                int* __restrict__ cidx,
                                                float* __restrict__ cxyz,
                                                float* __restrict__ out) {
#pragma clang fp contract(off)
  __shared__ float sx[NN], sy[NN], sz[NN];
  __shared__ unsigned long long s_best[2][8];
  __shared__ int   s_pidx[MM];
  __shared__ float s_px[MM], s_py[MM], s_pz[MM];
  const int t = threadIdx.x;
  const int b = blockIdx.x;
  const float* xb = pc + (size_t)b * NN * 6;
  v2f px[8], py[8], pz[8], dist[8];
#pragma unroll
  for (int j = 0; j < 8; ++j) {
    int p0 = t + (2*j)*512, p1 = t + (2*j+1)*512;
    float X0 = xb[(size_t)p0*6+0], Y0 = xb[(size_t)p0*6+1], Z0 = xb[(size_t)p0*6+2];
    float X1 = xb[(size_t)p1*6+0], Y1 = xb[(size_t)p1*6+1], Z1 = xb[(size_t)p1*6+2];
    px[j] = (v2f){X0, X1}; py[j] = (v2f){Y0, Y1}; pz[j] = (v2f){Z0, Z1};
    dist[j] = (v2f){1e10f, 1e10f};
    sx[p0] = X0; sy[p0] = Y0; sz[p0] = Z0;
    sx[p1] = X1; sy[p1] = Y1; sz[p1] = Z1;
  }
  __syncthreads();
  float lx = sx[0], ly = sy[0], lz = sz[0];
  if (t == 0) { s_pidx[0] = 0; s_px[0] = lx; s_py[0] = ly; s_pz[0] = lz; }
  const int lane = t & 63, wave = t >> 6;
  for (int step = 1; step < MM; ++step) {
    float bvA = -1.0f, bvB = -1.0f; int bpA = 0, bpB = 0;
#pragma unroll
    for (int j = 0; j < 8; ++j) {
      v2f dx = px[j] - lx, dy = py[j] - ly, dz = pz[j] - lz;
      v2f d = (dx*dx + dy*dy) + dz*dz;       // contract(off): exact numpy order
      v2f nd = __builtin_elementwise_min(dist[j], d);
      dist[j] = nd;
      float nA = nd.x, nB = nd.y;
      if (nA > bvA) { bvA = nA; bpA = t + (2*j)*512; }    // stream A: p ascending
      if (nB > bvB) { bvB = nB; bpB = t + (2*j+1)*512; }  // stream B: p ascending
    }
    // exact tie handling across streams via packed keys (tie -> smaller p)
    unsigned long long kA = ((unsigned long long)__float_as_uint(bvA) << 32)
                          | (unsigned)(0xFFFFFFFFu - (unsigned)bpA);
    unsigned long long kB = ((unsigned long long)__float_as_uint(bvB) << 32)
                          | (unsigned)(0xFFFFFFFFu - (unsigned)bpB);
    unsigned long long key = (kB > kA) ? kB : kA;
    key = dpp_max_u64(key);              // VALU-only wave reduce; lane 63 valid
    if (lane == 63) s_best[step & 1][wave] = key;
    __syncthreads();                     // single barrier (parity dbuf)
    const ulonglong2* sb = (const ulonglong2*)s_best[step & 1];
    ulonglong2 q0 = sb[0], q1 = sb[1], q2 = sb[2], q3 = sb[3];
    unsigned long long kk = q0.x;
    if (q0.y > kk) kk = q0.y;
    if (q1.x > kk) kk = q1.x;
    if (q1.y > kk) kk = q1.y;
    if (q2.x > kk) kk = q2.x;
    if (q2.y > kk) kk = q2.y;
    if (q3.x > kk) kk = q3.x;
    if (q3.y > kk) kk = q3.y;
    int p = (int)(0xFFFFFFFFu - (unsigned)(kk & 0xFFFFFFFFull));
    lx = sx[p]; ly = sy[p]; lz = sz[p];  // LDS broadcast
    if (t == 0) {                        // LDS staging only (cheap lgkm)
      s_pidx[step] = p;
      s_px[step] = lx; s_py[step] = ly; s_pz[step] = lz;
    }
  }
  __syncthreads();
  // coalesced epilogue: write all selected indices/coords once
  if (t < MM) {
    int p = s_pidx[t];
    cidx[b*MM + t] = p;
    out[O_CIDX + b*MM + t] = (float)p;
    cxyz[((size_t)b*MM + t)*3+0] = s_px[t];
    cxyz[((size_t)b*MM + t)*3+1] = s_py[t];
    cxyz[((size_t)b*MM + t)*3+2] = s_pz[t];
  }
}

// ================= pack + p_fea + head: 1 point/thread, no LDS ===================
// amdgpu_waves_per_eu(1,2): 256-VGPR budget so acc[64]+h1[32] stay in registers.
// (Proven in R5/R6; do NOT change to other ranges — (3,8) caps regs at 64, spills.)
__attribute__((amdgpu_waves_per_eu(1, 2)))
__global__ __launch_bounds__(256) void k_pfea(const float* __restrict__ pc,
                                              const float* __restrict__ knn,
                                              const float* __restrict__ Wk1,
                                              const float* __restrict__ Wk2,
                                              const float* __restrict__ Wg,
                                              const float* __restrict__ hW1,
                                              const float* __restrict__ hW2,
                                              float* __restrict__ xyz,
                                              float* __restrict__ out) {
  int i = blockIdx.x * 256 + threadIdx.x;
  const float2* pr = (const float2*)(pc + (size_t)i*6);
  float2 r0 = pr[0], r1 = pr[1], r2 = pr[2];
  float* xo = xyz + (size_t)i*3;
  xo[0] = r0.x; xo[1] = r0.y; xo[2] = r1.x;
  float acc[DD];
#pragma unroll
  for (int d = 0; d < DD; ++d) acc[d] = -3.4e38f;
  const float* kp = knn + (size_t)i * NSAMP * 2;
  for (int s = 0; s < NSAMP; ++s) {
    float u = kp[s*2+0], v2 = kp[s*2+1];
    float h1[32];
#pragma unroll
    for (int j = 0; j < 32; ++j) h1[j] = fmaxf(u*Wk1[j] + v2*Wk1[32+j], 0.f);
#pragma unroll
    for (int d = 0; d < DD; ++d) {
      float tt = 0.f;
#pragma unroll
      for (int j = 0; j < 32; ++j) tt += h1[j]*Wk2[j*DD+d];
      acc[d] = fmaxf(acc[d], tt);
    }
  }
  float f0 = r1.y, f1 = r2.x, f2 = r2.y;
#pragma unroll
  for (int d = 0; d < DD; ++d) {
    float hg = fmaxf(f0*Wg[d] + f1*Wg[DD+d] + f2*Wg[2*DD+d], 0.f);
    acc[d] = fmaxf(acc[d], 0.f) + hg;          // final p_fea value
    out[O_PFEA + (size_t)i*DD + d] = acc[d];
  }
  // fused head MLP: out = relu(p_fea @ hW1) @ hW2
  float o[CC];
#pragma unroll
  for (int c = 0; c < CC; ++c) o[c] = 0.f;
  for (int d = 0; d < DD; ++d) {
    float t1 = 0.f;
#pragma unroll
    for (int j = 0; j < DD; ++j) t1 += acc[j]*hW1[j*DD+d];
    t1 = fmaxf(t1, 0.f);
#pragma unroll
    for (int c = 0; c < CC; ++c) o[c] += t1*hW2[d*CC+c];
  }
#pragma unroll
  for (int c = 0; c < CC; ++c) out[O_OUT + (size_t)i*CC + c] = o[c];
}

// ---------------- 6-NN cluster search (stable top-k) ----------------
__global__ __launch_bounds__(256) void k_knn(const float* __restrict__ xyz,
                      const float* __restrict__ cxyz,
                      const int* __restrict__ cidx, int* __restrict__ c2p,
                      float* __restrict__ out) {
  __shared__ float4 sc[MM];
  int i = blockIdx.x * 256 + threadIdx.x;
  int b = i >> 13;
  for (int m = threadIdx.x; m < MM; m += 256) {
    sc[m] = make_float4(cxyz[((size_t)b*MM+m)*3+0], cxyz[((size_t)b*MM+m)*3+1],
                        cxyz[((size_t)b*MM+m)*3+2], 0.f);
  }
  __syncthreads();
  float x = xyz[(size_t)i*3+0], y = xyz[(size_t)i*3+1], z = xyz[(size_t)i*3+2];
  float dv[KK]; int di[KK];
#pragma unroll
  for (int j = 0; j < KK; ++j) { dv[j] = 3.4e38f; di[j] = 0; }
  for (int m = 0; m < MM; ++m) {
    float4 c = sc[m];
    float dx = x - c.x, dy = y - c.y, dz = z - c.z;
    float d = __fadd_rn(__fadd_rn(__fmul_rn(dx,dx), __fmul_rn(dy,dy)), __fmul_rn(dz,dz));
    if (d < dv[KK-1]) {
      float v = d; int vi = m; bool ins = false;
#pragma unroll
      for (int j = 0; j < KK; ++j) {
        bool doit = ins || (v < dv[j]);   // strict <: stable top_k
        float tv = doit ? dv[j] : v; int ti = doit ? di[j] : vi;
        if (doit) { dv[j] = v; di[j] = vi; }
        v = tv; vi = ti; ins = doit;
      }
    }
  }
#pragma unroll
  for (int k = 0; k < KK; ++k) {
    c2p[(size_t)i*KK+k] = di[k];
    out[O_C2PA + (size_t)i*KK + k] = (float)di[k];
    out[O_C2P  + (size_t)i*KK + k] = (float)cidx[b*MM + di[k]];
  }
}

// ---------------- fused CSR build + pseudo-label: one block per batch ----------
__global__ __launch_bounds__(1024) void k_csr(const int* __restrict__ c2p,
                                              const int* __restrict__ label,
                                              int* __restrict__ cnt_g,
                                              int* __restrict__ offs_g,
                                              int* __restrict__ entries,
                                              float* __restrict__ out) {
  __shared__ int s_cnt[MM];
  __shared__ int s_off[MM];
  __shared__ int s_cur[MM];
  __shared__ int s_lab[MM*CC];
  int b = blockIdx.x, t = threadIdx.x;
  for (int i = t; i < MM; i += 1024) s_cnt[i] = 0;
  for (int i = t; i < MM*CC; i += 1024) s_lab[i] = 0;
  __syncthreads();
  const int* cb = c2p + (size_t)b*NN*KK;
  const int* lb = label + (size_t)b*NN;
  for (int n = t; n < NN; n += 1024) {
    int lab = lb[n];
#pragma unroll
    for (int k = 0; k < KK; ++k) {
      int m = cb[(size_t)n*KK+k];
      atomicAdd(&s_cnt[m], 1);
      atomicAdd(&s_lab[m*CC+lab], 1);
    }
  }
  __syncthreads();
  if (t < MM) s_off[t] = s_cnt[t];
  __syncthreads();
  for (int off = 1; off < MM; off <<= 1) {
    int v = 0;
    if (t < MM && t >= off) v = s_off[t-off];
    __syncthreads();
    if (t < MM && t >= off) s_off[t] += v;
    __syncthreads();
  }
  if (t < MM) {
    int ex = (t == 0) ? 0 : s_off[t-1];
    s_cur[t] = ex;
    offs_g[b*MM+t] = ex;
    cnt_g[b*MM+t] = s_cnt[t];
    int best = 0, bv = s_lab[t*CC];
#pragma unroll
    for (int c = 1; c < CC; ++c) { int v = s_lab[t*CC+c]; if (v > bv) { bv = v; best = c; } }
    out[O_PSLAB + b*MM + t] = (float)best;
#pragma unroll
    for (int c = 0; c < CC; ++c)
      out[O_PSOH + ((size_t)b*CC + c)*MM + t] = (c == best) ? 1.0f : 0.0f;
  }
  __syncthreads();
  for (int n = t; n < NN; n += 1024) {
#pragma unroll
    for (int k = 0; k < KK; ++k) {
      int m = cb[(size_t)n*KK+k];
      int pos = atomicAdd(&s_cur[m], 1);
      entries[(size_t)b*NN*KK + pos] = n*KK + k;
    }
  }
}

// ---------------- weighted scatter + fused sf@Wf1 (smeta) ----------------
// w==null     : init mode (w=1, sp_xyz=cxyz, den floor 1.0)
// onehot!=null: also produce sp_label (+ transposed output)
// Wf1n!=null  : produce smeta for the NEXT slic layer
__global__ __launch_bounds__(256, 1) void k_scat(const float* __restrict__ pfea,
                          const float* __restrict__ xyz,
                          const float* __restrict__ w,
                          const float* __restrict__ cxyz,
                          const float* __restrict__ onehot,
                          const int* __restrict__ entries, const int* __restrict__ offs,
                          const int* __restrict__ cnt,
                          const float* __restrict__ Wf1n,
                          float* __restrict__ sp_fea, float* __restrict__ sp_xyz,
                          float* __restrict__ sp_label, float* __restrict__ smeta,
                          float* __restrict__ out) {
  int bm = blockIdx.x;
  int b = bm >> 9, m = bm & (MM-1);
  int t = threadIdx.x;
  int wv = t >> 6, lane = t & 63;
  int base = b*NN*KK;
  int st = offs[bm], n_e = cnt[bm];
  __shared__ int   s_ent[1024];
  __shared__ float s_w[1024];
  __shared__ float s_f[4][DD], s_x[4][4], s_l[4][16], s_d[4];
  __shared__ float s_sf[DD], s_part[16][17];
  float acc = 0.f, accx = 0.f, accl = 0.f, den = 0.f;
  for (int c0 = 0; c0 < n_e; c0 += 1024) {
    int cn = min(1024, n_e - c0);
    __syncthreads();
    for (int e = t; e < cn; e += 256) {
      int ee = entries[base + st + c0 + e];
      s_ent[e] = ee;
      s_w[e] = w ? w[(size_t)base + ee] : 1.0f;
    }
    __syncthreads();
    for (int e = wv; e < cn; e += 4) {
      int ee = s_ent[e]; float ww = s_w[e];
      int n = ee / KK;
      acc += ww * pfea[((size_t)b*NN+n)*DD + lane];
      if (lane < 3) accx += ww * xyz[((size_t)b*NN+n)*3 + lane];
      if (onehot && lane < CC) accl += ww * onehot[((size_t)b*NN+n)*CC + lane];
      den += ww;
    }
  }
  s_f[wv][lane] = acc;
  if (lane < 4)  s_x[wv][lane] = (lane < 3) ? accx : 0.f;
  if (lane < 16) s_l[wv][lane] = (lane < CC) ? accl : 0.f;
  if (lane == 0) s_d[wv] = den;
  __syncthreads();
  if (wv == 0) {
    float A  = s_f[0][lane] + s_f[1][lane] + s_f[2][lane] + s_f[3][lane];
    float Dn = s_d[0] + s_d[1] + s_d[2] + s_d[3];
    float dv = w ? fmaxf(Dn, 1e-8f) : fmaxf(Dn, 1.0f);
    float sfv = A / dv;
    sp_fea[(size_t)bm*DD + lane] = sfv;
    s_sf[lane] = sfv;
    if (lane < 3) {
      float X = w ? (s_x[0][lane]+s_x[1][lane]+s_x[2][lane]+s_x[3][lane]) / dv
                  : cxyz[bm*3+lane];
      sp_xyz[bm*3+lane] = X;
      if (Wf1n) smeta[bm*20 + 16 + lane] = X;
    }
    if (onehot && lane < CC) {
      float L = (s_l[0][lane]+s_l[1][lane]+s_l[2][lane]+s_l[3][lane]) / fmaxf(Dn, 1e-8f);
      sp_label[(size_t)bm*CC + lane] = L;
      out[O_SPLABT + ((size_t)b*CC + lane)*MM + m] = L;
    }
  }
  if (Wf1n) {
    __syncthreads();
    int c = t & 15, part = t >> 4;
    float pr = 0.f;
#pragma unroll
    for (int q = 0; q < 4; ++q)
      pr += s_sf[part*4+q] * Wf1n[(part*4+q)*16 + c];
    s_part[part][c] = pr;
    __syncthreads();
    if (t < 16) {
      float sm = 0.f;
#pragma unroll
      for (int q = 0; q < 16; ++q) sm += s_part[q][t];
      smeta[bm*20 + t] = sm;
    }
  }
}

// ---------------- SLIC weight computation (one iteration) ----------------
// (1,2): 256-VGPR budget; ~150 live regs (pf[64] + 6x16 arrays) stay in registers.
__attribute__((amdgpu_waves_per_eu(1, 2)))
__global__ __launch_bounds__(256) void k_slicw(const float* __restrict__ pfea,
                        const float* __restrict__ xyz,
                        const float* __restrict__ smeta,
                        const int* __restrict__ c2p,
                        const float* __restrict__ Wf1, const float* __restrict__ Wf2,
                        const float* __restrict__ Wx1, const float* __restrict__ Wx2,
                        const float* __restrict__ Wm1, const float* __restrict__ Wm2,
                        float* __restrict__ wout, float* __restrict__ wout2) {
  int i = blockIdx.x*256 + threadIdx.x;
  int b = i >> 13;
  float pf[DD];
  const float4* pf4 = (const float4*)(pfea + (size_t)i*DD);
#pragma unroll
  for (int q = 0; q < DD/4; ++q) {
    float4 t = pf4[q];
    pf[q*4+0] = t.x; pf[q*4+1] = t.y; pf[q*4+2] = t.z; pf[q*4+3] = t.w;
  }
  float a[16];
#pragma unroll
  for (int c = 0; c < 16; ++c) a[c] = 0.f;
#pragma unroll
  for (int d = 0; d < DD; ++d) {
    float f = pf[d];
#pragma unroll
    for (int c = 0; c < 16; ++c) a[c] += f*Wm1[d*16+c];
  }
  float pm[16];
#pragma unroll
  for (int c2 = 0; c2 < 16; ++c2) {
    float t = 0.f;
#pragma unroll
    for (int c = 0; c < 16; ++c) t += fmaxf(a[c], 0.f)*Wm2[c*16+c2];
    pm[c2] = fmaxf(t, 0.f);
  }
  float pfd[16];
#pragma unroll
  for (int c = 0; c < 16; ++c) pfd[c] = 0.f;
#pragma unroll
  for (int d = 0; d < DD; ++d) {
    float f = pf[d];
#pragma unroll
    for (int c = 0; c < 16; ++c) pfd[c] += f*Wf1[d*16+c];
  }
  float x = xyz[(size_t)i*3+0], y = xyz[(size_t)i*3+1], z = xyz[(size_t)i*3+2];
  float lg[KK];
#pragma unroll 1
  for (int k = 0; k < KK; ++k) {
    int m = c2p[(size_t)i*KK+k];
    int bm = (b << 9) + m;
    const float4* mp = (const float4*)(smeta + (size_t)bm*20);
    float4 m0 = mp[0], m1 = mp[1], m2 = mp[2], m3 = mp[3], m4 = mp[4];
    float wa[16];
    wa[0]=m0.x-pfd[0];  wa[1]=m0.y-pfd[1];  wa[2]=m0.z-pfd[2];  wa[3]=m0.w-pfd[3];
    wa[4]=m1.x-pfd[4];  wa[5]=m1.y-pfd[5];  wa[6]=m1.z-pfd[6];  wa[7]=m1.w-pfd[7];
    wa[8]=m2.x-pfd[8];  wa[9]=m2.y-pfd[9];  wa[10]=m2.z-pfd[10]; wa[11]=m2.w-pfd[11];
    wa[12]=m3.x-pfd[12]; wa[13]=m3.y-pfd[13]; wa[14]=m3.z-pfd[14]; wa[15]=m3.w-pfd[15];
    float wf[16];
#pragma unroll
    for (int c2 = 0; c2 < 16; ++c2) {
      float t = 0.f;
#pragma unroll
      for (int c = 0; c < 16; ++c) t += fmaxf(wa[c], 0.f)*Wf2[c*16+c2];
      wf[c2] = fmaxf(t, 0.f);
    }
    float dx = m4.x - x, dy = m4.y - y, dz = m4.z - z;
    float ax[16];
#pragma unroll
    for (int c = 0; c < 16; ++c)
      ax[c] = fmaxf(dx*Wx1[c] + dy*Wx1[16+c] + dz*Wx1[32+c], 0.f);
    float lgk = 0.f;
#pragma unroll
    for (int c2 = 0; c2 < 16; ++c2) {
      float t = 0.f;
#pragma unroll
      for (int c = 0; c < 16; ++c) t += ax[c]*Wx2[c*16+c2];
      lgk += fmaxf(t, 0.f)*wf[c2]*pm[c2];
    }
    lg[k] = lgk;
  }
  float mx = lg[0];
#pragma unroll
  for (int k = 1; k < KK; ++k) mx = fmaxf(mx, lg[k]);
  float e[KK], s = 0.f;
#pragma unroll
  for (int k = 0; k < KK; ++k) { e[k] = expf(lg[k]-mx); s += e[k]; }
#pragma unroll
  for (int k = 0; k < KK; ++k) {
    float wv = e[k]/s;
    wout[(size_t)i*KK+k] = wv;
    if (wout2) wout2[(size_t)i*KK+k] = wv;
  }
}

// ---------------- per-point finalization ----------------
__global__ __launch_bounds__(256) void k_final(const float* __restrict__ sp_xyz, const float* __restrict__ sp_label,
                        const int* __restrict__ c2p, float* __restrict__ out) {
  int i = blockIdx.x*256 + threadIdx.x;
  int b = i >> 13;
  float w[KK]; int id[KK];
#pragma unroll
  for (int k = 0; k < KK; ++k) {
    w[k] = out[O_ASSO + (size_t)i*KK+k];
    id[k] = c2p[(size_t)i*KK+k];
  }
  int best = 0; float bv = w[0];
#pragma unroll
  for (int k = 1; k < KK; ++k) if (w[k] > bv) { bv = w[k]; best = k; }
  int sel = id[best];
#pragma unroll
  for (int c = 0; c < 3; ++c)
    out[O_RPXYZ + (size_t)i*3+c] = sp_xyz[((size_t)b*MM+sel)*3+c];
  float acc[CC];
#pragma unroll
  for (int c = 0; c < CC; ++c) acc[c] = 0.f;
#pragma unroll
  for (int k = 0; k < KK; ++k) {
    const float* sl = sp_label + ((size_t)b*MM + id[k])*CC;
    float ww = w[k];
#pragma unroll
    for (int c = 0; c < CC; ++c) acc[c] += ww*sl[c];
  }
#pragma unroll
  for (int c = 0; c < CC; ++c) out[O_RPLAB + (size_t)i*CC+c] = acc[c];
}

// ---------------- launcher ----------------
extern "C" void kernel_launch(void* const* d_in, const int* in_sizes, int n_in,
                              void* d_out, int out_size, void* d_ws, size_t ws_size,
                              hipStream_t stream) {
  const float* pc     = (const float*)d_in[0];
  const float* knn    = (const float*)d_in[1];
  const float* onehot = (const float*)d_in[2];
  const int*   label  = (const int*)d_in[3];
  const float* Wk1    = (const float*)d_in[4];
  const float* Wk2    = (const float*)d_in[5];
  const float* Wg     = (const float*)d_in[6];
  const float* hW1    = (const float*)d_in[7];
  const float* hW2    = (const float*)d_in[8];
  const float* Wf1    = (const float*)d_in[9];
  const float* Wf2    = (const float*)d_in[10];
  const float* Wx1    = (const float*)d_in[11];
  const float* Wx2    = (const float*)d_in[12];
  const float* Wm1    = (const float*)d_in[13];
  const float* Wm2    = (const float*)d_in[14];
  float* out = (float*)d_out;

  float* wsf = (float*)d_ws;
  size_t o = 0;
  float* xyz     = wsf + o; o += (size_t)BB*NN*3;
  float* cxyz    = wsf + o; o += (size_t)BB*MM*3;
  int*   cidx    = (int*)(wsf + o); o += BB*MM;
  int*   c2p     = (int*)(wsf + o); o += (size_t)BB*NN*KK;
  int*   cnt     = (int*)(wsf + o); o += BB*MM;
  int*   offs    = (int*)(wsf + o); o += BB*MM;
  int*   entries = (int*)(wsf + o); o += (size_t)BB*NN*KK;
  float* sp_fea  = wsf + o; o += (size_t)BB*MM*DD;
  float* sp_xyz  = wsf + o; o += (size_t)BB*MM*3;
  float* sp_label= wsf + o; o += (size_t)BB*MM*CC;
  float* smeta   = wsf + o; o += (size_t)BB*MM*20;

  k_fps  <<<BB, 512, 0, stream>>>(pc, cidx, cxyz, out);
  k_pfea <<<BB*NN/256, 256, 0, stream>>>(pc, knn, Wk1, Wk2, Wg, hW1, hW2, xyz, out);
  k_knn  <<<BB*NN/256, 256, 0, stream>>>(xyz, cxyz, cidx, c2p, out);
  k_csr  <<<BB, 1024, 0, stream>>>(c2p, label, cnt, offs, entries, out);
  // init: sp_fea = mean, sp_xyz = cluster_xyz, smeta for layer 0
  k_scat<<<BB*MM, 256, 0, stream>>>(out + O_PFEA, xyz, nullptr, cxyz, nullptr,
      entries, offs, cnt, Wf1 /*layer0*/, sp_fea, sp_xyz, nullptr, smeta, out);
  for (int l = 0; l < 4; ++l) {
    k_slicw<<<BB*NN/256, 256, 0, stream>>>(out + O_PFEA, xyz, smeta, c2p,
        Wf1 + l*DD*16, Wf2 + l*256, Wx1 + l*48, Wx2 + l*256,
        Wm1 + l*DD*16, Wm2 + l*256,
        out + O_ASSO, (l == 3) ? (out + O_FDIST) : nullptr);
    k_scat<<<BB*MM, 256, 0, stream>>>(out + O_PFEA, xyz, out + O_ASSO, cxyz,
        (l == 3) ? onehot : nullptr, entries, offs, cnt,
        (l < 3) ? (Wf1 + (l+1)*DD*16) : nullptr,
        sp_fea, sp_xyz, sp_label, smeta, out);
  }
  k_final<<<BB*NN/256, 256, 0, stream>>>(sp_xyz, sp_label, c2p, out);
}